// Round 1
// baseline (114.717 us; speedup 1.0000x reference)
//
#include <hip/hip_runtime.h>

#define M_ 32
#define T_ 50
#define NX_ 192
#define NY_ 192
#define NG_ 50
#define H_ 4
#define D_ 8
#define P_ (NG_*NG_)

// workspace layout in 4-byte units
#define WS_W    0                 // 32 floats: combined weights
#define WS_XI   32                // 50 ints:   x cell index
#define WS_XT   82                // 50 floats: x fraction
#define WS_XIN  132               // 50 floats: x inside mask
#define WS_YJ   192               // 1600 ints:   y cell index per (m,iy)
#define WS_YT   (192+1600)        // 1600 floats: y fraction
#define WS_YIN  (192+3200)        // 1600 floats: y inside mask
#define WS_TOTAL (192+4800)

__global__ void prep_kernel(const float* __restrict__ params_src,
                            const float* __restrict__ tgt_params,
                            const float* __restrict__ W_q,
                            const float* __restrict__ W_k,
                            const float* __restrict__ src_xgrid,
                            const float* __restrict__ src_ygrid,
                            float* __restrict__ wsf) {
  int* wsi = (int*)wsf;
  const int tid = threadIdx.x;
  const float ly_t = tgt_params[0];

  if (tid == 0) {
    // ---- attention + gaussian weights, serial f32 (tiny) ----
    float nt0 = (tgt_params[0] - 30.0f) / 90.0f;
    float nt1 = tgt_params[1] / 0.0029f;
    float nt2 = tgt_params[2] / 0.0018f;
    float q[H_ * D_];
    for (int o = 0; o < H_ * D_; o++)
      q[o] = nt0 * W_q[o * 3 + 0] + nt1 * W_q[o * 3 + 1] + nt2 * W_q[o * 3 + 2];

    float ns[M_][3];
    float logits[M_][H_];
    const float inv_sqrt_d = 1.0f / sqrtf(8.0f);
    for (int m = 0; m < M_; m++) {
      ns[m][0] = (params_src[m * 3 + 0] - 30.0f) / 90.0f;
      ns[m][1] = params_src[m * 3 + 1] / 0.0029f;
      ns[m][2] = params_src[m * 3 + 2] / 0.0018f;
      for (int h = 0; h < H_; h++) {
        float acc = 0.0f;
        for (int d = 0; d < D_; d++) {
          int o = h * D_ + d;
          float kk = ns[m][0] * W_k[o * 3 + 0] + ns[m][1] * W_k[o * 3 + 1] +
                     ns[m][2] * W_k[o * 3 + 2];
          acc += kk * q[o];
        }
        logits[m][h] = acc * inv_sqrt_d;
      }
    }
    float attn[M_];
    for (int m = 0; m < M_; m++) attn[m] = 0.0f;
    for (int h = 0; h < H_; h++) {
      float mx = -3.0e38f;
      for (int m = 0; m < M_; m++) mx = fmaxf(mx, logits[m][h]);
      float e[M_]; float s = 0.0f;
      for (int m = 0; m < M_; m++) { e[m] = expf(logits[m][h] - mx); s += e[m]; }
      for (int m = 0; m < M_; m++) attn[m] += e[m] / s;
    }
    float sw[M_];
    float ssum = 0.0f;
    for (int m = 0; m < M_; m++) {
      attn[m] *= 0.25f;  // mean over H
      float d0 = (ns[m][0] - nt0) / 0.2f;
      float d1 = (ns[m][1] - nt1) / 0.2f;
      float d2v = (ns[m][2] - nt2) / 0.2f;
      float dd = d0 * d0 + d1 * d1 + d2v * d2v;
      sw[m] = expf(-dd * 0.5f);
      ssum += sw[m];
    }
    float w[M_];
    float tsum = 0.0f;
    for (int m = 0; m < M_; m++) {
      w[m] = attn[m] * (sw[m] / (ssum + 1e-8f));
      tsum += w[m];
    }
    for (int m = 0; m < M_; m++) wsf[WS_W + m] = w[m] / (tsum + 1e-8f);
  }

  // ---- x tables (all source x-grids identical; use row 0) ----
  for (int ix = tid; ix < NG_; ix += blockDim.x) {
    // numpy linspace(0,100,50): f64 step, exact endpoint
    float qx = (ix == NG_ - 1) ? 100.0f : (float)((double)ix * (100.0 / 49.0));
    int lo = 0, hi = NX_;  // searchsorted side='right'
    while (lo < hi) { int mid = (lo + hi) >> 1; if (src_xgrid[mid] <= qx) lo = mid + 1; else hi = mid; }
    int i = lo - 1; i = i < 0 ? 0 : (i > NX_ - 2 ? NX_ - 2 : i);
    float g0 = src_xgrid[i], g1 = src_xgrid[i + 1];
    wsi[WS_XI + ix] = i;
    wsf[WS_XT + ix] = (qx - g0) / (g1 - g0);
    wsf[WS_XIN + ix] = (qx >= src_xgrid[0] && qx <= src_xgrid[NX_ - 1]) ? 1.0f : 0.0f;
  }

  // ---- y tables per (m, iy): gy[j] = src_ygrid[m][j] * (ly_t/ly_m), exact f32 ops ----
  for (int idx = tid; idx < M_ * NG_; idx += blockDim.x) {
    int m = idx / NG_, iy = idx % NG_;
    float scale = ly_t / params_src[m * 3 + 0];
    float qy = ((iy == NG_ - 1) ? 1.0f : (float)((double)iy * (1.0 / 49.0))) * ly_t;
    const float* gy = src_ygrid + m * NY_;
    int lo = 0, hi = NY_;
    while (lo < hi) { int mid = (lo + hi) >> 1; if (gy[mid] * scale <= qy) lo = mid + 1; else hi = mid; }
    int j = lo - 1; j = j < 0 ? 0 : (j > NY_ - 2 ? NY_ - 2 : j);
    float g0 = gy[j] * scale, g1 = gy[j + 1] * scale;
    wsi[WS_YJ + idx] = j;
    wsf[WS_YT + idx] = (qy - g0) / (g1 - g0);
    wsf[WS_YIN + idx] =
        (qy >= gy[0] * scale && qy <= gy[NY_ - 1] * scale) ? 1.0f : 0.0f;
  }
}

__global__ __launch_bounds__(256) void interp_kernel(
    const float* __restrict__ c1, const float* __restrict__ c2,
    const float* __restrict__ tgt_params, const float* __restrict__ wsf,
    float* __restrict__ out) {
  const int* wsi = (const int*)wsf;
  __shared__ float s_w[M_];
  __shared__ int   s_xi[NG_];
  __shared__ float s_xt[NG_];
  __shared__ float s_xin[NG_];
  __shared__ int   s_yj[M_ * NG_];
  __shared__ float s_yt[M_ * NG_];
  __shared__ float s_yin[M_ * NG_];

  for (int i = threadIdx.x; i < M_; i += blockDim.x) s_w[i] = wsf[WS_W + i];
  for (int i = threadIdx.x; i < NG_; i += blockDim.x) {
    s_xi[i] = wsi[WS_XI + i];
    s_xt[i] = wsf[WS_XT + i];
    s_xin[i] = wsf[WS_XIN + i];
  }
  for (int i = threadIdx.x; i < M_ * NG_; i += blockDim.x) {
    s_yj[i] = wsi[WS_YJ + i];
    s_yt[i] = wsf[WS_YT + i];
    s_yin[i] = wsf[WS_YIN + i];
  }
  __syncthreads();

  int g = blockIdx.x * blockDim.x + threadIdx.x;
  if (g >= T_ * P_) return;
  int t = g / P_;
  int p = g % P_;
  int ix = p / NG_, iy = p % NG_;

  int i = s_xi[ix];
  float fx = s_xt[ix];
  float insx = s_xin[ix];
  float acc1 = 0.0f, acc2 = 0.0f;

  for (int m = 0; m < M_; m++) {
    int j = s_yj[m * NG_ + iy];
    float fy = s_yt[m * NG_ + iy];
    float ins = insx * s_yin[m * NG_ + iy];
    size_t base = ((size_t)(m * T_ + t) * NX_ + i) * NY_ + j;
    float a00 = c1[base], a01 = c1[base + 1];
    float a10 = c1[base + NY_], a11 = c1[base + NY_ + 1];
    float b00 = c2[base], b01 = c2[base + 1];
    float b10 = c2[base + NY_], b11 = c2[base + NY_ + 1];
    float wx0 = 1.0f - fx, wy0 = 1.0f - fy;
    float v1 = a00 * wx0 * wy0 + a10 * fx * wy0 + a01 * wx0 * fy + a11 * fx * fy;
    float v2 = b00 * wx0 * wy0 + b10 * fx * wy0 + b01 * wx0 * fy + b11 * fx * fy;
    float wm = s_w[m] * ins;
    acc1 += wm * v1;
    acc2 += wm * v2;
  }

  // boundary conditions
  float ccu = tgt_params[1], cni = tgt_params[2];
  if (iy == 0) acc1 = ccu;
  if (iy == NG_ - 1) acc2 = cni;

  out[g] = acc1;            // [0,t,ix,iy]
  out[T_ * P_ + g] = acc2;  // [1,t,ix,iy]
}

extern "C" void kernel_launch(void* const* d_in, const int* in_sizes, int n_in,
                              void* d_out, int out_size, void* d_ws, size_t ws_size,
                              hipStream_t stream) {
  const float* params_src = (const float*)d_in[0];
  const float* tgt_params = (const float*)d_in[1];
  const float* c1 = (const float*)d_in[2];
  const float* c2 = (const float*)d_in[3];
  const float* W_q = (const float*)d_in[4];
  const float* W_k = (const float*)d_in[5];
  const float* src_xgrid = (const float*)d_in[6];
  const float* src_ygrid = (const float*)d_in[7];
  float* out = (float*)d_out;
  float* wsf = (float*)d_ws;

  prep_kernel<<<1, 256, 0, stream>>>(params_src, tgt_params, W_q, W_k,
                                     src_xgrid, src_ygrid, wsf);
  int total = T_ * P_;
  int blocks = (total + 255) / 256;
  interp_kernel<<<blocks, 256, 0, stream>>>(c1, c2, tgt_params, wsf, out);
}